// Round 3
// baseline (204.376 us; speedup 1.0000x reference)
//
#include <hip/hip_runtime.h>

// Problem constants
constexpr int      FRAMES  = 128 * 1024;              // B*T = 131072
constexpr int      FRAME_F = 150;                     // floats per frame
constexpr unsigned NT      = (unsigned)FRAMES * 50u;  // 6,553,600 bone triples
// final = 0.1 * (sum_abs + 0.1*sum_sq) / (FRAMES*150)
constexpr float    SCALE   = 0.1f / ((float)FRAMES * (float)FRAME_F);

constexpr int      BLOCK   = 256;
constexpr int      NBLK    = 2048;                    // partials = 8 KB (proven size)
constexpr unsigned G       = (unsigned)NBLK * BLOCK;  // 524,288 threads
constexpr unsigned NC      = NT / 4u;                 // 1,638,400 chunks of 4 triples
constexpr int      FULL    = (int)(NC / G);           // 3 full phases/thread
constexpr unsigned TAILN   = NC - (unsigned)FULL * G; // 65,536 tail chunks

// One bone term from raw (unmasked) self triple (p,t) and neighbor triple (q,u).
__device__ __forceinline__ float bone_term(
    float p0, float p1, float p2, float t0, float t1, float t2,
    float q0, float q1, float q2, float u0, float u1, float u2)
{
    // masks: targets*mask == targets identically; mask preds only
    const float m0 = (t0 != 0.0f) ? 1.0f : 0.0f;
    const float m1 = (t1 != 0.0f) ? 1.0f : 0.0f;
    const float m2 = (t2 != 0.0f) ? 1.0f : 0.0f;
    const float n0 = (u0 != 0.0f) ? 1.0f : 0.0f;
    const float n1 = (u1 != 0.0f) ? 1.0f : 0.0f;
    const float n2 = (u2 != 0.0f) ? 1.0f : 0.0f;

    const float pm0 = p0 * m0, pm1 = p1 * m1, pm2 = p2 * m2;
    const float qm0 = q0 * n0, qm1 = q1 * n1, qm2 = q2 * n2;

    // L1 term over this triple
    const float ab = fabsf(pm0 - t0) + fabsf(pm1 - t1) + fabsf(pm2 - t2);

    // bone direction term
    const float pd0 = pm0 - qm0, pd1 = pm1 - qm1, pd2 = pm2 - qm2;
    const float td0 = t0 - u0,   td1 = t1 - u1,   td2 = t2 - u2;

    const float pl2 = pd0*pd0 + pd1*pd1 + pd2*pd2;
    const float tl2 = td0*td0 + td1*td1 + td2*td2;
    const float pri = (pl2 > 0.0f) ? __builtin_amdgcn_rsqf(pl2) : 0.0f;
    const float tri = (tl2 > 0.0f) ? __builtin_amdgcn_rsqf(tl2) : 0.0f;

    const float d0 = pd0 * pri - td0 * tri;
    const float d1 = pd1 * pri - td1 * tri;
    const float d2 = pd2 * pri - td2 * tri;
    const float sq = m0*d0*d0 + m1*d1*d1 + m2*d2*d2;  // mask[:, :, :150] re-mask

    return ab + 0.1f * sq;
}

// One chunk of 4 consecutive triples starting at triple index c*4 (48 B,
// 16-B aligned). All loads into NAMED float4/scalar registers (no arrays ->
// nothing the compiler can demote to scratch): 3x dwordx4 + 2x dwordx3 per
// input array = 10 clustered loads per phase.
// j of triple k is (j0+k)%50 with j0 even; the wrap-neighbor case (j==49)
// can only occur at k=1 (j0==48) or k=3 (j0==46).
__device__ __forceinline__ float chunk4(const float* __restrict__ preds,
                                        const float* __restrict__ targets,
                                        unsigned c)
{
    const unsigned bt = c * 4u;                 // base triple index
    const unsigned j0 = bt % 50u;               // even residue
    const float* P = preds   + (size_t)bt * 3u;
    const float* T = targets + (size_t)bt * 3u;

    // successor triple (neighbor of k=3 when it doesn't wrap); when j0==46
    // k=3 wraps -> successor unused and may be OOB (last chunk) -> clamp to 0
    const int eoff = (j0 == 46u) ? 0 : 12;
    // frame start of the wrapping triple: index bt+kw-49, kw = 49-j0
    // j0==48 -> -144 floats, j0==46 -> -138 floats; else unused -> 0 (L1 merge)
    const int woff = (j0 == 48u) ? -144 : (j0 == 46u) ? -138 : 0;

    // ---- load phase: named registers only ----
    const float4 pa = *reinterpret_cast<const float4*>(P + 0);
    const float4 pb = *reinterpret_cast<const float4*>(P + 4);
    const float4 pc = *reinterpret_cast<const float4*>(P + 8);
    const float4 ta = *reinterpret_cast<const float4*>(T + 0);
    const float4 tb = *reinterpret_cast<const float4*>(T + 4);
    const float4 tc = *reinterpret_cast<const float4*>(T + 8);
    const float ps0 = P[eoff+0], ps1 = P[eoff+1], ps2 = P[eoff+2];
    const float ts0 = T[eoff+0], ts1 = T[eoff+1], ts2 = T[eoff+2];
    const float pw0 = P[woff+0], pw1 = P[woff+1], pw2 = P[woff+2];
    const float tw0 = T[woff+0], tw1 = T[woff+1], tw2 = T[woff+2];

    const bool w1 = (j0 == 48u);
    const bool w3 = (j0 == 46u);

    // ---- compute phase: neighbors are register lane-slides ----
    float acc = bone_term(pa.x, pa.y, pa.z,  ta.x, ta.y, ta.z,
                          pa.w, pb.x, pb.y,  ta.w, tb.x, tb.y);       // k=0
    acc += bone_term(pa.w, pb.x, pb.y,  ta.w, tb.x, tb.y,
                     w1 ? pw0 : pb.z, w1 ? pw1 : pb.w, w1 ? pw2 : pc.x,
                     w1 ? tw0 : tb.z, w1 ? tw1 : tb.w, w1 ? tw2 : tc.x); // k=1
    acc += bone_term(pb.z, pb.w, pc.x,  tb.z, tb.w, tc.x,
                     pc.y, pc.z, pc.w,  tc.y, tc.z, tc.w);            // k=2
    acc += bone_term(pc.y, pc.z, pc.w,  tc.y, tc.z, tc.w,
                     w3 ? pw0 : ps0, w3 ? pw1 : ps1, w3 ? pw2 : ps2,
                     w3 ? tw0 : ts0, w3 ? tw1 : ts1, w3 ? tw2 : ts2); // k=3
    return acc;
}

__global__ __launch_bounds__(BLOCK, 4) void bone_loss_main(
    const float* __restrict__ preds,
    const float* __restrict__ targets,
    float* __restrict__ partials)
{
    const unsigned tid = blockIdx.x * BLOCK + threadIdx.x;

    float acc = chunk4(preds, targets, tid);
    acc += chunk4(preds, targets, tid + G);
    acc += chunk4(preds, targets, tid + 2u * G);
    if (tid < TAILN)                                   // blocks 0..255 only
        acc += chunk4(preds, targets, tid + 3u * G);

    // ---- block reduction ----
    #pragma unroll
    for (int off = 32; off > 0; off >>= 1)
        acc += __shfl_down(acc, off, 64);

    __shared__ float ws[4];
    const int wid = threadIdx.x >> 6;
    if ((threadIdx.x & 63) == 0) ws[wid] = acc;
    __syncthreads();
    if (threadIdx.x == 0)
        partials[blockIdx.x] = ws[0] + ws[1] + ws[2] + ws[3];
}

__global__ __launch_bounds__(256) void bone_loss_finish(
    const float* __restrict__ partials,
    float* __restrict__ out)
{
    float v = 0.0f;
    for (int i = threadIdx.x; i < NBLK; i += 256)
        v += partials[i];

    #pragma unroll
    for (int off = 32; off > 0; off >>= 1)
        v += __shfl_down(v, off, 64);

    __shared__ float ws[4];
    const int wid = threadIdx.x >> 6;
    if ((threadIdx.x & 63) == 0) ws[wid] = v;
    __syncthreads();
    if (threadIdx.x == 0)
        out[0] = (ws[0] + ws[1] + ws[2] + ws[3]) * SCALE;
}

extern "C" void kernel_launch(void* const* d_in, const int* in_sizes, int n_in,
                              void* d_out, int out_size, void* d_ws, size_t ws_size,
                              hipStream_t stream) {
    const float* preds   = (const float*)d_in[0];
    const float* targets = (const float*)d_in[1];
    float* out      = (float*)d_out;
    float* partials = (float*)d_ws;       // NBLK floats = 8 KB

    bone_loss_main<<<NBLK, BLOCK, 0, stream>>>(preds, targets, partials);
    bone_loss_finish<<<1, 256, 0, stream>>>(partials, out);
}

// Round 4
// 178.059 us; speedup vs baseline: 1.1478x; 1.1478x over previous
//
#include <hip/hip_runtime.h>

// Problem constants
constexpr int   FRAMES  = 128 * 1024;    // B*T = 131072
constexpr int   FRAME_F = 150;           // floats per frame
// final = 0.1 * (sum_abs + 0.1*sum_sq) / (FRAMES*150)
constexpr float SCALE   = 0.1f / ((float)FRAMES * (float)FRAME_F);

constexpr int BLOCK    = 256;
constexpr int SFRAMES  = 16;                   // frames per stage
constexpr int STRIPLES = SFRAMES * 50;         // 800 triples / stage
constexpr int SFLOATS  = SFRAMES * FRAME_F;    // 2400 floats = 9600 B / array
constexpr int SSEGS    = SFLOATS / 4;          // 600 16-B segments / array
constexpr int NBLK     = 1024;                 // 4 blocks/CU (LDS-bound)
constexpr int NSTAGES  = FRAMES / SFRAMES;     // 8192
constexpr int SPB      = NSTAGES / NBLK;       // 8 stages per block, exact

typedef __attribute__((address_space(1))) const void  gvoid;
typedef __attribute__((address_space(3)))       void  lvoid;

// One bone term from raw (unmasked) self triple (p,t) and neighbor triple (q,u).
__device__ __forceinline__ float bone_term(
    float p0, float p1, float p2, float t0, float t1, float t2,
    float q0, float q1, float q2, float u0, float u1, float u2)
{
    // masks: targets*mask == targets identically; mask preds only
    const float m0 = (t0 != 0.0f) ? 1.0f : 0.0f;
    const float m1 = (t1 != 0.0f) ? 1.0f : 0.0f;
    const float m2 = (t2 != 0.0f) ? 1.0f : 0.0f;
    const float n0 = (u0 != 0.0f) ? 1.0f : 0.0f;
    const float n1 = (u1 != 0.0f) ? 1.0f : 0.0f;
    const float n2 = (u2 != 0.0f) ? 1.0f : 0.0f;

    const float pm0 = p0 * m0, pm1 = p1 * m1, pm2 = p2 * m2;
    const float qm0 = q0 * n0, qm1 = q1 * n1, qm2 = q2 * n2;

    // L1 term over this triple
    const float ab = fabsf(pm0 - t0) + fabsf(pm1 - t1) + fabsf(pm2 - t2);

    // bone direction term
    const float pd0 = pm0 - qm0, pd1 = pm1 - qm1, pd2 = pm2 - qm2;
    const float td0 = t0 - u0,   td1 = t1 - u1,   td2 = t2 - u2;

    const float pl2 = pd0*pd0 + pd1*pd1 + pd2*pd2;
    const float tl2 = td0*td0 + td1*td1 + td2*td2;
    const float pri = (pl2 > 0.0f) ? __builtin_amdgcn_rsqf(pl2) : 0.0f;
    const float tri = (tl2 > 0.0f) ? __builtin_amdgcn_rsqf(tl2) : 0.0f;

    const float d0 = pd0 * pri - td0 * tri;
    const float d1 = pd1 * pri - td1 * tri;
    const float d2 = pd2 * pri - td2 * tri;
    const float sq = m0*d0*d0 + m1*d1*d1 + m2*d2*d2;  // mask[:, :, :150] re-mask

    return ab + 0.1f * sq;
}

// Issue the async global->LDS staging for one stage (both arrays).
// Per wave: it0/it1 fully active, it2 active only for seg<600
//   -> waves 0,1 issue 3 insts/array (6 total), waves 2,3 issue 2 (4 total).
// LDS dest is wave-uniform base; HW scatters lane l at base + l*16.
__device__ __forceinline__ void stage_issue(const float4* __restrict__ gp,
                                            const float4* __restrict__ gt,
                                            float4* lp, float4* lt,
                                            int wid, int lane)
{
    #pragma unroll
    for (int it = 0; it < 3; ++it) {
        const int segb = it * 256 + wid * 64;   // wave-uniform
        const int seg  = segb + lane;
        if (seg < SSEGS) {
            __builtin_amdgcn_global_load_lds((gvoid*)(gp + seg), (lvoid*)(lp + segb), 16, 0, 0);
            __builtin_amdgcn_global_load_lds((gvoid*)(gt + seg), (lvoid*)(lt + segb), 16, 0, 0);
        }
    }
}

// Consume one staged buffer: 800 triples, thread tid handles idx = it*256+tid.
__device__ __forceinline__ float compute_stage(const float* __restrict__ lp,
                                               const float* __restrict__ lt,
                                               int tid, int j0)
{
    float acc = 0.0f;
    #pragma unroll
    for (int it = 0; it < 4; ++it) {
        const int idx = it * 256 + tid;
        if (idx < STRIPLES) {                       // it==3: only tid<32
            int j = j0 + (it * 256) % 50;           // +{0,6,12,18}, compile-time
            if (j >= 50) j -= 50;
            const int nidx = (j == 49) ? idx - 49 : idx + 1;   // wrap stays in stage
            const int s = idx * 3, n = nidx * 3;
            acc += bone_term(lp[s+0], lp[s+1], lp[s+2],
                             lt[s+0], lt[s+1], lt[s+2],
                             lp[n+0], lp[n+1], lp[n+2],
                             lt[n+0], lt[n+1], lt[n+2]);
        }
    }
    return acc;
}

__global__ __launch_bounds__(BLOCK, 4) void bone_loss_main(
    const float* __restrict__ preds,
    const float* __restrict__ targets,
    float* __restrict__ partials)
{
    __shared__ float4 ldsP[2][SSEGS];   // 19.2 KB
    __shared__ float4 ldsT[2][SSEGS];   // 19.2 KB  (38.4 KB total -> 4 blocks/CU)

    const int tid  = threadIdx.x;
    const int wid  = tid >> 6;
    const int lane = tid & 63;
    const int j0   = tid % 50;
    const int s0   = blockIdx.x * SPB;  // contiguous stage range per block (L2 locality)

    const float4* gp = reinterpret_cast<const float4*>(preds);
    const float4* gt = reinterpret_cast<const float4*>(targets);

    // prologue: stage 0 into buffer 0
    stage_issue(gp + (size_t)s0 * SSEGS, gt + (size_t)s0 * SSEGS,
                ldsP[0], ldsT[0], wid, lane);

    float acc = 0.0f;
    for (int i = 0; i < SPB; ++i) {
        const int c = i & 1;

        // prefetch next stage into the other buffer (stays in flight across barrier)
        if (i + 1 < SPB)
            stage_issue(gp + (size_t)(s0 + i + 1) * SSEGS,
                        gt + (size_t)(s0 + i + 1) * SSEGS,
                        ldsP[c ^ 1], ldsT[c ^ 1], wid, lane);

        // counted wait: own older (current-buffer) loads done; newer stay in flight.
        if (i + 1 < SPB) {
            if (wid < 2) asm volatile("s_waitcnt vmcnt(6)" ::: "memory");
            else         asm volatile("s_waitcnt vmcnt(4)" ::: "memory");
        } else {
            asm volatile("s_waitcnt vmcnt(0)" ::: "memory");
        }
        __builtin_amdgcn_s_barrier();           // all waves' shares of buffer c landed
        asm volatile("" ::: "memory");          // no LDS-read hoist above the barrier

        acc += compute_stage((const float*)ldsP[c], (const float*)ldsT[c], tid, j0);

        asm volatile("" ::: "memory");          // no LDS-read sink below the barrier
        __builtin_amdgcn_s_barrier();           // all waves done reading c; safe to restage
    }

    // ---- block reduction ----
    #pragma unroll
    for (int off = 32; off > 0; off >>= 1)
        acc += __shfl_down(acc, off, 64);

    __shared__ float ws[4];
    if (lane == 0) ws[wid] = acc;
    __syncthreads();
    if (tid == 0)
        partials[blockIdx.x] = ws[0] + ws[1] + ws[2] + ws[3];
}

__global__ __launch_bounds__(256) void bone_loss_finish(
    const float* __restrict__ partials,
    float* __restrict__ out)
{
    float v = 0.0f;
    for (int i = threadIdx.x; i < NBLK; i += 256)
        v += partials[i];

    #pragma unroll
    for (int off = 32; off > 0; off >>= 1)
        v += __shfl_down(v, off, 64);

    __shared__ float ws[4];
    const int wid = threadIdx.x >> 6;
    if ((threadIdx.x & 63) == 0) ws[wid] = v;
    __syncthreads();
    if (threadIdx.x == 0)
        out[0] = (ws[0] + ws[1] + ws[2] + ws[3]) * SCALE;
}

extern "C" void kernel_launch(void* const* d_in, const int* in_sizes, int n_in,
                              void* d_out, int out_size, void* d_ws, size_t ws_size,
                              hipStream_t stream) {
    const float* preds   = (const float*)d_in[0];
    const float* targets = (const float*)d_in[1];
    float* out      = (float*)d_out;
    float* partials = (float*)d_ws;       // NBLK floats = 4 KB

    bone_loss_main<<<NBLK, BLOCK, 0, stream>>>(preds, targets, partials);
    bone_loss_finish<<<1, 256, 0, stream>>>(partials, out);
}

// Round 5
// 175.956 us; speedup vs baseline: 1.1615x; 1.0119x over previous
//
#include <hip/hip_runtime.h>

// Problem constants
constexpr int      FRAMES  = 128 * 1024;              // B*T = 131072
constexpr int      FRAME_F = 150;                     // floats per frame
constexpr unsigned NT      = (unsigned)FRAMES * 50u;  // 6,553,600 bone triples
constexpr unsigned NC      = NT / 4u;                 // 1,638,400 chunks of 4 triples
// final = 0.1 * (sum_abs + 0.1*sum_sq) / (FRAMES*150)
constexpr float    SCALE   = 0.1f / ((float)FRAMES * (float)FRAME_F);

constexpr int      BLOCK   = 256;
constexpr int      NBLK    = 2048;                    // partials = 8 KB (proven)
constexpr unsigned G       = (unsigned)NBLK * BLOCK;  // 524,288 threads; ~3.125 chunks/thread

// One bone term from raw (unmasked) self triple (p,t) and neighbor triple (q,u).
__device__ __forceinline__ float bone_term(
    float p0, float p1, float p2, float t0, float t1, float t2,
    float q0, float q1, float q2, float u0, float u1, float u2)
{
    // masks: targets*mask == targets identically; mask preds only
    const float m0 = (t0 != 0.0f) ? 1.0f : 0.0f;
    const float m1 = (t1 != 0.0f) ? 1.0f : 0.0f;
    const float m2 = (t2 != 0.0f) ? 1.0f : 0.0f;
    const float n0 = (u0 != 0.0f) ? 1.0f : 0.0f;
    const float n1 = (u1 != 0.0f) ? 1.0f : 0.0f;
    const float n2 = (u2 != 0.0f) ? 1.0f : 0.0f;

    const float pm0 = p0 * m0, pm1 = p1 * m1, pm2 = p2 * m2;
    const float qm0 = q0 * n0, qm1 = q1 * n1, qm2 = q2 * n2;

    // L1 term over this triple
    const float ab = fabsf(pm0 - t0) + fabsf(pm1 - t1) + fabsf(pm2 - t2);

    // bone direction term
    const float pd0 = pm0 - qm0, pd1 = pm1 - qm1, pd2 = pm2 - qm2;
    const float td0 = t0 - u0,   td1 = t1 - u1,   td2 = t2 - u2;

    const float pl2 = pd0*pd0 + pd1*pd1 + pd2*pd2;
    const float tl2 = td0*td0 + td1*td1 + td2*td2;
    const float pri = (pl2 > 0.0f) ? __builtin_amdgcn_rsqf(pl2) : 0.0f;
    const float tri = (tl2 > 0.0f) ? __builtin_amdgcn_rsqf(tl2) : 0.0f;

    const float d0 = pd0 * pri - td0 * tri;
    const float d1 = pd1 * pri - td1 * tri;
    const float d2 = pd2 * pri - td2 * tri;
    const float sq = m0*d0*d0 + m1*d1*d1 + m2*d2*d2;  // mask[:, :, :150] re-mask

    return ab + 0.1f * sq;
}

__global__ __launch_bounds__(BLOCK, 4) void bone_loss_main(
    const float* __restrict__ preds,
    const float* __restrict__ targets,
    float* __restrict__ partials)
{
    const unsigned tid = blockIdx.x * BLOCK + threadIdx.x;
    float acc = 0.0f;

    // One 4-triple chunk per iteration; unroll DISABLED so only one chunk's
    // loads are ever live (R2/R3 proved that hoisting multiple chunks' loads
    // into one live range forces scratch spill). TLP (8 waves/SIMD), not ILP,
    // hides latency; within a chunk the 8 dwordx4 + 2 dwordx3 issue back-to-back.
    #pragma clang loop unroll(disable)
    for (unsigned c = tid; c < NC; c += G) {
        const unsigned bt = c * 4u;                 // base triple, j0 = bt%50 even
        const unsigned j0 = bt % 50u;
        const float* P = preds   + (size_t)bt * 3u; // byte 48c, 16-B aligned
        const float* T = targets + (size_t)bt * 3u;

        const bool w1 = (j0 == 48u);                // k=1 neighbor wraps (j==49)
        const bool w3 = (j0 == 46u);                // k=3 neighbor wraps
        // successor chunk-start triple (neighbor of k=3 when no wrap); clamp
        // to own base when w3 (unused there; keeps the final chunk in-bounds)
        const int eoff = w3 ? 0 : 12;
        // frame-start triple of the wrapping bone (always >= array start)
        const int woff = w1 ? -144 : (w3 ? -138 : 0);

        // ---- loads: 4x dwordx4 per array + 1 small wrap read, all named ----
        const float4 pa = *reinterpret_cast<const float4*>(P + 0);
        const float4 pb = *reinterpret_cast<const float4*>(P + 4);
        const float4 pc = *reinterpret_cast<const float4*>(P + 8);
        const float4 ps = *reinterpret_cast<const float4*>(P + eoff);
        const float4 ta = *reinterpret_cast<const float4*>(T + 0);
        const float4 tb = *reinterpret_cast<const float4*>(T + 4);
        const float4 tc = *reinterpret_cast<const float4*>(T + 8);
        const float4 ts = *reinterpret_cast<const float4*>(T + eoff);
        const float pw0 = P[woff+0], pw1 = P[woff+1], pw2 = P[woff+2];
        const float tw0 = T[woff+0], tw1 = T[woff+1], tw2 = T[woff+2];

        // ---- 4 bone terms; neighbors are register lane-slides ----
        acc += bone_term(pa.x, pa.y, pa.z,  ta.x, ta.y, ta.z,
                         pa.w, pb.x, pb.y,  ta.w, tb.x, tb.y);            // k=0
        acc += bone_term(pa.w, pb.x, pb.y,  ta.w, tb.x, tb.y,
                         w1 ? pw0 : pb.z, w1 ? pw1 : pb.w, w1 ? pw2 : pc.x,
                         w1 ? tw0 : tb.z, w1 ? tw1 : tb.w, w1 ? tw2 : tc.x); // k=1
        acc += bone_term(pb.z, pb.w, pc.x,  tb.z, tb.w, tc.x,
                         pc.y, pc.z, pc.w,  tc.y, tc.z, tc.w);            // k=2
        acc += bone_term(pc.y, pc.z, pc.w,  tc.y, tc.z, tc.w,
                         w3 ? pw0 : ps.x, w3 ? pw1 : ps.y, w3 ? pw2 : ps.z,
                         w3 ? tw0 : ts.x, w3 ? tw1 : ts.y, w3 ? tw2 : ts.z); // k=3
    }

    // ---- block reduction ----
    #pragma unroll
    for (int off = 32; off > 0; off >>= 1)
        acc += __shfl_down(acc, off, 64);

    __shared__ float ws[4];
    const int wid = threadIdx.x >> 6;
    if ((threadIdx.x & 63) == 0) ws[wid] = acc;
    __syncthreads();
    if (threadIdx.x == 0)
        partials[blockIdx.x] = ws[0] + ws[1] + ws[2] + ws[3];
}

__global__ __launch_bounds__(256) void bone_loss_finish(
    const float* __restrict__ partials,
    float* __restrict__ out)
{
    float v = 0.0f;
    for (int i = threadIdx.x; i < NBLK; i += 256)
        v += partials[i];

    #pragma unroll
    for (int off = 32; off > 0; off >>= 1)
        v += __shfl_down(v, off, 64);

    __shared__ float ws[4];
    const int wid = threadIdx.x >> 6;
    if ((threadIdx.x & 63) == 0) ws[wid] = v;
    __syncthreads();
    if (threadIdx.x == 0)
        out[0] = (ws[0] + ws[1] + ws[2] + ws[3]) * SCALE;
}

extern "C" void kernel_launch(void* const* d_in, const int* in_sizes, int n_in,
                              void* d_out, int out_size, void* d_ws, size_t ws_size,
                              hipStream_t stream) {
    const float* preds   = (const float*)d_in[0];
    const float* targets = (const float*)d_in[1];
    float* out      = (float*)d_out;
    float* partials = (float*)d_ws;       // NBLK floats = 8 KB

    bone_loss_main<<<NBLK, BLOCK, 0, stream>>>(preds, targets, partials);
    bone_loss_finish<<<1, 256, 0, stream>>>(partials, out);
}